// Round 3
// baseline (281.163 us; speedup 1.0000x reference)
//
#include <hip/hip_runtime.h>

typedef float f4 __attribute__((ext_vector_type(4)));

constexpr int N_  = 4;
constexpr int C_  = 320;
constexpr int H_  = 80;
constexpr int W_  = 160;
constexpr int G_  = 40;
constexpr int CPG = 8;      // channels per group
constexpr int D_  = 48;     // max disparity
constexpr int PAD = 48;     // zero pad in front of R rows
constexpr int RW  = PAD + W_;   // 208 floats per R row
constexpr int TILES = (W_ / 4) * (D_ / 8);   // 40*6 = 240 4w x 8d tiles per block

__global__ __launch_bounds__(256) void gw_cost_kernel(const float* __restrict__ Lg,
                                                      const float* __restrict__ Rg,
                                                      float* __restrict__ out) {
    __shared__ float Ls[CPG * W_];    // 8 x 160              (5120 B)
    __shared__ float Rs[CPG * RW];    // 8 x 208, rw<48 zero  (6656 B)

    const int blk = blockIdx.x;               // ((n*G + g)*H + h)
    const int tid = threadIdx.x;

    const int h = blk % H_;
    const int g = (blk / H_) % G_;
    const int n = blk / (H_ * G_);

    // ---- stage global -> LDS (f4, 16B-aligned; each byte read exactly once globally) ----
    for (int i = tid; i < CPG * (W_ / 4); i += 256) {   // 320 f4 per input
        const int c  = i / 40;
        const int w4 = i % 40;
        const float* gp = Lg + ((size_t)(n * C_ + g * CPG + c) * H_ + h) * W_ + w4 * 4;
        const float* gq = Rg + ((size_t)(n * C_ + g * CPG + c) * H_ + h) * W_ + w4 * 4;
        *(f4*)&Ls[c * W_ + w4 * 4]        = __builtin_nontemporal_load((const f4*)gp);
        *(f4*)&Rs[c * RW + PAD + w4 * 4]  = __builtin_nontemporal_load((const f4*)gq);
    }
    for (int i = tid; i < CPG * (PAD / 4); i += 256) {  // 96 zero f4
        const int c  = i / 12;
        const int p4 = i % 12;
        *(f4*)&Rs[c * RW + p4 * 4] = (f4)(0.0f);
    }
    __syncthreads();

    if (tid < TILES) {
        const int tw = tid / 6;
        const int td = tid % 6;
        const int w0 = tw * 4;
        const int d0 = td * 8;
        const int r0 = w0 - d0 + PAD;      // in [8, 204]; reads r0-8 .. r0+3 within [0,207]

        f4 acc[4][2] = {};

        #pragma unroll
        for (int c = 0; c < CPG; ++c) {
            const f4 lv = *(const f4*)&Ls[c * W_ + w0];
            const float* rp = &Rs[c * RW + (r0 - 8)];   // 16B-aligned
            const f4 ra = *(const f4*)(rp);
            const f4 rb = *(const f4*)(rp + 4);
            const f4 rc = *(const f4*)(rp + 8);
            float r[12];
            #pragma unroll
            for (int k = 0; k < 4; ++k) { r[k] = ra[k]; r[4 + k] = rb[k]; r[8 + k] = rc[k]; }
            // out(w0+i, d0+j) += L[w0+i] * R[r0 + i - j]  -> r[8 + i - j]
            #pragma unroll
            for (int i = 0; i < 4; ++i) {
                #pragma unroll
                for (int j = 0; j < 8; ++j) {
                    acc[i][j >> 2][j & 3] += lv[i] * r[8 + i - j];
                }
            }
        }

        float* op = out + (size_t)blk * (W_ * D_) + (size_t)w0 * D_ + d0;
        #pragma unroll
        for (int i = 0; i < 4; ++i) {
            __builtin_nontemporal_store(acc[i][0] * 0.125f, (f4*)(op + i * D_));
            __builtin_nontemporal_store(acc[i][1] * 0.125f, (f4*)(op + i * D_ + 4));
        }
    }
}

extern "C" void kernel_launch(void* const* d_in, const int* in_sizes, int n_in,
                              void* d_out, int out_size, void* d_ws, size_t ws_size,
                              hipStream_t stream) {
    const float* Lg = (const float*)d_in[0];
    const float* Rg = (const float*)d_in[1];
    float* out = (float*)d_out;

    const int nblocks = N_ * G_ * H_;   // 12800 blocks, one per (n, g, h)
    gw_cost_kernel<<<dim3(nblocks), dim3(256), 0, stream>>>(Lg, Rg, out);
}

// Round 4
// 123.693 us; speedup vs baseline: 2.2731x; 2.2731x over previous
//
#include <hip/hip_runtime.h>

typedef float f4 __attribute__((ext_vector_type(4)));

constexpr int N_  = 4;
constexpr int C_  = 320;
constexpr int H_  = 80;
constexpr int W_  = 160;
constexpr int G_  = 40;
constexpr int CPG = 8;                      // channels per group
constexpr int D_  = 48;                     // max disparity
constexpr int PAD = 48;                     // zero pad in front of R rows
constexpr int RW  = PAD + W_;               // 208 floats per R row
constexpr int HC  = 10;                     // h-rows streamed per block
constexpr int NCH = H_ / HC;                // 8 chunks
constexpr int TILES = (W_ / 4) * (D_ / 8);  // 240 4w x 8d tiles per row
constexpr int NF4 = 2 * CPG * (W_ / 4);     // 640 staged f4 per row (L:320, R:320)

// ---- T14 split: issue global loads early (to regs) ----
__device__ __forceinline__ void stage_load(const float* __restrict__ Lg,
                                           const float* __restrict__ Rg,
                                           size_t bng, int h, f4 (&r)[3], int tid) {
    #pragma unroll
    for (int k = 0; k < 3; ++k) {
        const int i = tid + k * 256;
        if (i < NF4) {
            // i<320 -> L f4 #i ; else R f4 #(i-320). Channel stride = H*W floats.
            const int  j  = (i < 320) ? i : (i - 320);
            const int  c  = j / 40, w4 = j % 40;
            const float* src = ((i < 320) ? Lg : Rg) + bng + (size_t)c * (H_ * W_)
                               + (size_t)h * W_ + w4 * 4;
            r[k] = *(const f4*)src;
        }
    }
}

// ---- write regs -> LDS buffer b (late, after compute) ----
__device__ __forceinline__ void stage_write(float* __restrict__ LsB,
                                            float* __restrict__ RsB,
                                            const f4 (&r)[3], int tid) {
    #pragma unroll
    for (int k = 0; k < 3; ++k) {
        const int i = tid + k * 256;
        if (i < NF4) {
            if (i < 320) {
                const int c = i / 40, w4 = i % 40;
                *(f4*)&LsB[c * W_ + w4 * 4] = r[k];
            } else {
                const int j = i - 320;
                const int c = j / 40, w4 = j % 40;
                *(f4*)&RsB[c * RW + PAD + w4 * 4] = r[k];
            }
        }
    }
}

__global__ __launch_bounds__(256) void gw_cost_kernel(const float* __restrict__ Lg,
                                                      const float* __restrict__ Rg,
                                                      float* __restrict__ out) {
    __shared__ float Ls[2][CPG * W_];   // 2 x 5120 B
    __shared__ float Rs[2][CPG * RW];   // 2 x 6656 B, rw<48 is zero pad

    const int tid = threadIdx.x;
    const int blk = blockIdx.x;                 // ((n*G + g)*NCH + hc)
    const int hc = blk % NCH;
    const int g  = (blk / NCH) % G_;
    const int n  = blk / (NCH * G_);
    const int h0 = hc * HC;

    const size_t bng = (size_t)(n * C_ + g * CPG) * (H_ * W_);

    // zero the R pads in both buffers, once
    if (tid < 2 * CPG * (PAD / 4)) {            // 192 f4
        const int b = tid / (CPG * (PAD / 4));
        const int q = tid % (CPG * (PAD / 4));
        const int c = q / 12, p4 = q % 12;
        *(f4*)&Rs[b][c * RW + p4 * 4] = (f4)(0.0f);
    }

    f4 rbuf[3];

    // prologue: stage row h0 into buffer 0
    stage_load(Lg, Rg, bng, h0, rbuf, tid);
    stage_write(Ls[0], Rs[0], rbuf, tid);
    __syncthreads();

    // tile coords (fixed per thread)
    const int tw = tid / 6;
    const int td = tid % 6;
    const int w0 = tw * 4;
    const int d0 = td * 8;
    const int r0 = w0 - d0 + PAD;               // [8, 204]; reads r0-8 .. r0+3 in [0, 207]

    for (int hh = 0; hh < HC; ++hh) {
        const int cur  = hh & 1;
        const bool more = (hh + 1 < HC);

        // issue next row's global loads NOW; they complete under compute+stores
        if (more) stage_load(Lg, Rg, bng, h0 + hh + 1, rbuf, tid);

        if (tid < TILES) {
            const float* LsC = Ls[cur];
            const float* RsC = Rs[cur];
            f4 acc[4][2] = {};
            #pragma unroll
            for (int c = 0; c < CPG; ++c) {
                const f4 lv = *(const f4*)&LsC[c * W_ + w0];
                const float* rp = &RsC[c * RW + (r0 - 8)];   // 16B-aligned
                const f4 ra = *(const f4*)(rp);
                const f4 rb = *(const f4*)(rp + 4);
                const f4 rc = *(const f4*)(rp + 8);
                float r[12];
                #pragma unroll
                for (int k = 0; k < 4; ++k) { r[k] = ra[k]; r[4 + k] = rb[k]; r[8 + k] = rc[k]; }
                // out(w0+i, d0+j) += L[w0+i] * R[r0 + i - j]  -> r[8 + i - j]
                #pragma unroll
                for (int i = 0; i < 4; ++i) {
                    #pragma unroll
                    for (int j = 0; j < 8; ++j) {
                        acc[i][j >> 2][j & 3] += lv[i] * r[8 + i - j];
                    }
                }
            }
            float* op = out + ((size_t)((n * G_ + g) * H_ + h0 + hh)) * (W_ * D_)
                        + (size_t)w0 * D_ + d0;
            #pragma unroll
            for (int i = 0; i < 4; ++i) {
                *(f4*)(op + i * D_)     = acc[i][0] * 0.125f;
                *(f4*)(op + i * D_ + 4) = acc[i][1] * 0.125f;
            }
        }

        // write the prefetched row into the other buffer, then sync
        if (more) stage_write(Ls[cur ^ 1], Rs[cur ^ 1], rbuf, tid);
        __syncthreads();
    }
}

extern "C" void kernel_launch(void* const* d_in, const int* in_sizes, int n_in,
                              void* d_out, int out_size, void* d_ws, size_t ws_size,
                              hipStream_t stream) {
    const float* Lg = (const float*)d_in[0];
    const float* Rg = (const float*)d_in[1];
    float* out = (float*)d_out;

    const int nblocks = N_ * G_ * NCH;   // 1280 blocks = 5 resident per CU, all co-resident
    gw_cost_kernel<<<dim3(nblocks), dim3(256), 0, stream>>>(Lg, Rg, out);
}

// Round 5
// 120.854 us; speedup vs baseline: 2.3265x; 1.0235x over previous
//
#include <hip/hip_runtime.h>

typedef float f4 __attribute__((ext_vector_type(4)));

constexpr int N_  = 4;
constexpr int C_  = 320;
constexpr int H_  = 80;
constexpr int W_  = 160;
constexpr int G_  = 40;
constexpr int CPG = 8;                       // channels per group
constexpr int D_  = 48;                      // max disparity
constexpr int PAD = 48;                      // zero pad in front of R rows
constexpr int RW  = PAD + W_;                // 208 floats per R row
constexpr int TILES = (W_ / 4) * (D_ / 4);   // 480 4w x 4d tiles per row
constexpr int ROWS  = N_ * G_ * H_;          // 12800 (n,g,h) rows
constexpr int NBLK  = 2048;                  // persistent blocks = 8 per CU
constexpr int NF4   = 2 * CPG * (W_ / 4);    // 640 staged f4 per row

// issue global loads for row r early, into registers
__device__ __forceinline__ void stage_load(const float* __restrict__ Lg,
                                           const float* __restrict__ Rg,
                                           int r, f4 (&rb)[3], int tid) {
    const int h = r % H_;
    const int g = (r / H_) % G_;
    const int n = r / (H_ * G_);
    const size_t base = (size_t)(n * C_ + g * CPG) * (H_ * W_) + (size_t)h * W_;
    #pragma unroll
    for (int k = 0; k < 3; ++k) {
        const int i = tid + k * 256;
        if (i < NF4) {
            const int j = (i < 320) ? i : (i - 320);
            const int c = j / 40, w4 = j % 40;
            const float* src = ((i < 320) ? Lg : Rg) + base + (size_t)c * (H_ * W_) + w4 * 4;
            rb[k] = *(const f4*)src;
        }
    }
}

// write the prefetched registers into the (single) LDS buffer
__device__ __forceinline__ void stage_write(float* __restrict__ Ls,
                                            float* __restrict__ Rs,
                                            const f4 (&rb)[3], int tid) {
    #pragma unroll
    for (int k = 0; k < 3; ++k) {
        const int i = tid + k * 256;
        if (i < NF4) {
            if (i < 320) {
                const int c = i / 40, w4 = i % 40;
                *(f4*)&Ls[c * W_ + w4 * 4] = rb[k];
            } else {
                const int j = i - 320;
                const int c = j / 40, w4 = j % 40;
                *(f4*)&Rs[c * RW + PAD + w4 * 4] = rb[k];
            }
        }
    }
}

__global__ __launch_bounds__(256) void gw_cost_kernel(const float* __restrict__ Lg,
                                                      const float* __restrict__ Rg,
                                                      float* __restrict__ out) {
    __shared__ float Ls[CPG * W_];    // 5120 B
    __shared__ float Rs[CPG * RW];    // 6656 B, rw<48 stays zero

    const int tid = threadIdx.x;
    const int bid = blockIdx.x;

    // zero R pads once (never overwritten afterwards)
    for (int i = tid; i < CPG * (PAD / 4); i += 256) {
        const int c = i / 12, p4 = i % 12;
        *(f4*)&Rs[c * RW + p4 * 4] = (f4)(0.0f);
    }

    f4 rbuf[3];

    // prologue: stage first row
    stage_load(Lg, Rg, bid, rbuf, tid);
    stage_write(Ls, Rs, rbuf, tid);
    __syncthreads();

    for (int r = bid; r < ROWS; r += NBLK) {
        const int rn = r + NBLK;
        const bool more = (rn < ROWS);

        // issue next row's loads NOW; latency hides under compute+stores
        if (more) stage_load(Lg, Rg, rn, rbuf, tid);

        // ---- compute row r from LDS (R1's proven 4x4 core) ----
        for (int t = tid; t < TILES; t += 256) {
            const int tw = t / 12;
            const int td = t % 12;
            const int w0 = tw * 4;
            const int d0 = td * 4;
            const int r0 = w0 - d0 + PAD;   // [4, 204]; reads r0-4 .. r0+3 in [0, 207]

            f4 acc0 = (f4)(0.0f), acc1 = (f4)(0.0f), acc2 = (f4)(0.0f), acc3 = (f4)(0.0f);

            #pragma unroll
            for (int c = 0; c < CPG; ++c) {
                const f4 lv = *(const f4*)&Ls[c * W_ + w0];
                const float* rp = &Rs[c * RW + (r0 - 4)];  // 16B-aligned
                const f4 ra = *(const f4*)(rp);
                const f4 rb2 = *(const f4*)(rp + 4);
                float rr[8];
                #pragma unroll
                for (int k = 0; k < 4; ++k) { rr[k] = ra[k]; rr[4 + k] = rb2[k]; }
                // out(w0+i, d0+j) += L[w0+i] * R[r0 + i - j] -> rr[4 + i - j]
                #pragma unroll
                for (int j = 0; j < 4; ++j) {
                    acc0[j] += lv[0] * rr[4 + 0 - j];
                    acc1[j] += lv[1] * rr[4 + 1 - j];
                    acc2[j] += lv[2] * rr[4 + 2 - j];
                    acc3[j] += lv[3] * rr[4 + 3 - j];
                }
            }

            float* op = out + (size_t)r * (W_ * D_) + (size_t)w0 * D_ + d0;
            *(f4*)(op + 0 * D_) = acc0 * 0.125f;
            *(f4*)(op + 1 * D_) = acc1 * 0.125f;
            *(f4*)(op + 2 * D_) = acc2 * 0.125f;
            *(f4*)(op + 3 * D_) = acc3 * 0.125f;
        }

        if (more) {
            __syncthreads();                  // all waves done reading LDS
            stage_write(Ls, Rs, rbuf, tid);   // vmcnt wait lands here, already covered
            __syncthreads();                  // writes visible before next compute
        }
    }
}

extern "C" void kernel_launch(void* const* d_in, const int* in_sizes, int n_in,
                              void* d_out, int out_size, void* d_ws, size_t ws_size,
                              hipStream_t stream) {
    const float* Lg = (const float*)d_in[0];
    const float* Rg = (const float*)d_in[1];
    float* out = (float*)d_out;

    gw_cost_kernel<<<dim3(NBLK), dim3(256), 0, stream>>>(Lg, Rg, out);
}

// Round 6
// 106.722 us; speedup vs baseline: 2.6345x; 1.1324x over previous
//
#include <hip/hip_runtime.h>

typedef float f4 __attribute__((ext_vector_type(4)));

constexpr int N_  = 4;
constexpr int C_  = 320;
constexpr int H_  = 80;
constexpr int W_  = 160;
constexpr int G_  = 40;
constexpr int CPG = 8;                       // channels per group
constexpr int D_  = 48;                      // max disparity
constexpr int PAD = 48;                      // zero pad in front of R rows
constexpr int RW  = PAD + W_;                // 208 floats per R row
constexpr int HW  = H_ * W_;                 // channel stride in floats
constexpr int TILES = (W_ / 4) * (D_ / 4);   // 480 4w x 4d tiles per row

__global__ __launch_bounds__(256) void gw_cost_kernel(const float* __restrict__ Lg,
                                                      const float* __restrict__ Rg,
                                                      float* __restrict__ out) {
    __shared__ float Ls[CPG * W_];    // 5120 B
    __shared__ float Rs[CPG * RW];    // 6656 B, rw<48 is zero pad

    const int tid = threadIdx.x;
    const int blk = blockIdx.x;               // ((n*G + g)*H + h)

    const int h = blk % H_;
    const int g = (blk / H_) % G_;
    const int n = blk / (H_ * G_);

    const size_t rowbase = (size_t)(n * C_ + g * CPG) * HW + (size_t)h * W_;

    // zero the R pads: 96 f4, one ds_write for tid<96
    if (tid < CPG * (PAD / 4)) {
        const int c = tid / 12, p4 = tid % 12;
        *(f4*)&Rs[c * RW + p4 * 4] = (f4)(0.0f);
    }

    // ---- stage global -> LDS via direct DMA (no VGPR round-trip) ----
    // One instruction per (input, channel) row: 640 B = 40 lanes x 16 B.
    // LDS dest = wave-uniform base + lane*16 (linear, matches our layout);
    // global src is per-lane. Wave w handles channels {w, w+4}.
    const int wid  = tid >> 6;
    const int lane = tid & 63;
    if (lane < 40) {
        #pragma unroll
        for (int k = 0; k < 2; ++k) {
            const int c = wid + k * 4;
            const float* gl = Lg + rowbase + (size_t)c * HW + lane * 4;
            const float* gr = Rg + rowbase + (size_t)c * HW + lane * 4;
            __builtin_amdgcn_global_load_lds(
                (const __attribute__((address_space(1))) void*)gl,
                (__attribute__((address_space(3))) void*)&Ls[c * W_], 16, 0, 0);
            __builtin_amdgcn_global_load_lds(
                (const __attribute__((address_space(1))) void*)gr,
                (__attribute__((address_space(3))) void*)&Rs[c * RW + PAD], 16, 0, 0);
        }
    }
    __syncthreads();

    // ---- compute (R1's proven 4w x 4d core, unchanged) ----
    for (int t = tid; t < TILES; t += 256) {
        const int tw = t / 12;
        const int td = t % 12;
        const int w0 = tw * 4;
        const int d0 = td * 4;
        const int r0 = w0 - d0 + PAD;   // [4, 204]; reads r0-4 .. r0+3 within [0, 207]

        f4 acc0 = (f4)(0.0f), acc1 = (f4)(0.0f), acc2 = (f4)(0.0f), acc3 = (f4)(0.0f);

        #pragma unroll
        for (int c = 0; c < CPG; ++c) {
            const f4 lv = *(const f4*)&Ls[c * W_ + w0];
            const float* rp = &Rs[c * RW + (r0 - 4)];  // 16B-aligned
            const f4 ra = *(const f4*)(rp);
            const f4 rb = *(const f4*)(rp + 4);
            float rr[8];
            #pragma unroll
            for (int k = 0; k < 4; ++k) { rr[k] = ra[k]; rr[4 + k] = rb[k]; }
            // out(w0+i, d0+j) += L[w0+i] * R[r0 + i - j] -> rr[4 + i - j]
            #pragma unroll
            for (int j = 0; j < 4; ++j) {
                acc0[j] += lv[0] * rr[4 + 0 - j];
                acc1[j] += lv[1] * rr[4 + 1 - j];
                acc2[j] += lv[2] * rr[4 + 2 - j];
                acc3[j] += lv[3] * rr[4 + 3 - j];
            }
        }

        float* op = out + (size_t)blk * (W_ * D_) + (size_t)w0 * D_ + d0;
        *(f4*)(op + 0 * D_) = acc0 * 0.125f;
        *(f4*)(op + 1 * D_) = acc1 * 0.125f;
        *(f4*)(op + 2 * D_) = acc2 * 0.125f;
        *(f4*)(op + 3 * D_) = acc3 * 0.125f;
    }
}

extern "C" void kernel_launch(void* const* d_in, const int* in_sizes, int n_in,
                              void* d_out, int out_size, void* d_ws, size_t ws_size,
                              hipStream_t stream) {
    const float* Lg = (const float*)d_in[0];
    const float* Rg = (const float*)d_in[1];
    float* out = (float*)d_out;

    const int nblocks = N_ * G_ * H_;   // 12800 blocks, one per (n, g, h)
    gw_cost_kernel<<<dim3(nblocks), dim3(256), 0, stream>>>(Lg, Rg, out);
}